// Round 1
// baseline (293.384 us; speedup 1.0000x reference)
//
#include <hip/hip_runtime.h>
#include <string.h>

typedef unsigned short u16;
typedef unsigned int   u32;
typedef __attribute__((ext_vector_type(8))) short short8;     // 8 bf16/fp16 = 4 VGPRs
typedef __attribute__((ext_vector_type(4))) float f32x4;
typedef __attribute__((ext_vector_type(16))) float f32x16;
typedef __attribute__((ext_vector_type(2))) __fp16 h2;
typedef __attribute__((ext_vector_type(8))) __fp16 h8;
typedef __attribute__((ext_vector_type(2))) unsigned int u32x2;

// ---------- helpers ----------
__device__ __forceinline__ u16 f2b(float f) {                 // fp32 -> bf16 (RNE)
  u32 u = __float_as_uint(f);
  u32 r = (u + 0x7fffu + ((u >> 16) & 1u)) >> 16;
  return (u16)r;
}
// async global->LDS, 16B per lane; LDS dest = wave-uniform base + lane*16
__device__ __forceinline__ void cp16(const u16* g, u16* l) {
  __builtin_amdgcn_global_load_lds(
      (const __attribute__((address_space(1))) void*)g,
      (__attribute__((address_space(3))) void*)l, 16, 0, 0);
}
// v_permlane32_swap: a' = {a.lo32 | b.lo32}, b' = {a.hi32 | b.hi32}
__device__ __forceinline__ void plswap(u32& a, u32& b) {
  u32x2 r = __builtin_amdgcn_permlane32_swap(a, b, false, false);
  a = r[0]; b = r[1];
}

// ---------- fp32 -> bf16 conversion ----------
__global__ __launch_bounds__(256) void cvt_f2b_kernel(const float* __restrict__ in,
                                                      u16* __restrict__ out, int n) {
  int i = (blockIdx.x * 256 + threadIdx.x) * 4;
  if (i + 3 < n) {
    float4 v = *(const float4*)&in[i];
    ushort4 o = make_ushort4(f2b(v.x), f2b(v.y), f2b(v.z), f2b(v.w));
    *(ushort4*)&out[i] = o;
  }
}
// 4 weight matrices in one launch (blockIdx.y selects)
__global__ __launch_bounds__(256) void cvtw_kernel(const float* __restrict__ w0,
                                                   const float* __restrict__ w1,
                                                   const float* __restrict__ w2,
                                                   const float* __restrict__ w3,
                                                   u16* __restrict__ out) {
  const float* src = (blockIdx.y == 0) ? w0 : (blockIdx.y == 1) ? w1
                   : (blockIdx.y == 2) ? w2 : w3;
  int i = (blockIdx.x * 256 + threadIdx.x) * 4;
  float4 v = *(const float4*)&src[i];
  ushort4 o = make_ushort4(f2b(v.x), f2b(v.y), f2b(v.z), f2b(v.w));
  *(ushort4*)&out[(size_t)blockIdx.y * 1048576 + i] = o;
}

// ---------- bf16 MFMA GEMM, BK=32, SINGLE-BARRIER DBUF PIPELINE ----------
// (unchanged this round)
template<int MODE>
__global__ __launch_bounds__(256) void gemm128_bt(
    const u16* __restrict__ A, const u16* __restrict__ Bw,
    void* __restrict__ outp, const float* __restrict__ bias,
    const int M, const int N, const int K) {
  __shared__ __attribute__((aligned(16))) u16 As[2][128 * 32];
  __shared__ __attribute__((aligned(16))) u16 Bs[2][128 * 32];

  const u16* Bw2 = Bw;
  if (MODE == 0) Bw2 += ((size_t)blockIdx.z) << 20;

  const int tid  = threadIdx.x;
  const int wave = tid >> 6, lane = tid & 63;
  const int quad = lane >> 4, l15 = lane & 15;
  const int wm   = (wave >> 1) * 64, wn = (wave & 1) * 64;
  const int m0   = blockIdx.x * 128, n0 = blockIdx.y * 128;

  const int srow = wave * 32 + (lane >> 2);
  const int scol = (lane & 3) * 8;
  const u16* gA0 = A   + (size_t)(m0 + srow) * K + scol;
  const u16* gA1 = gA0 + (size_t)16 * K;
  const u16* gB0 = Bw2 + (size_t)(n0 + srow) * K + scol;
  const u16* gB1 = gB0 + (size_t)16 * K;
  const int lo0 = (wave * 32) * 32, lo1 = (wave * 32 + 16) * 32;

  cp16(gA0, &As[0][lo0]); cp16(gA1, &As[0][lo1]);
  cp16(gB0, &Bs[0][lo0]); cp16(gB1, &Bs[0][lo1]);
  gA0 += 32; gA1 += 32; gB0 += 32; gB1 += 32;

  f32x4 acc[4][4] = {};
  const int nk = K >> 5;
  for (int kt = 0; kt < nk; ++kt) {
    const int cur = kt & 1;
    __syncthreads();
    if (kt + 1 < nk) {
      cp16(gA0, &As[1 - cur][lo0]); cp16(gA1, &As[1 - cur][lo1]);
      cp16(gB0, &Bs[1 - cur][lo0]); cp16(gB1, &Bs[1 - cur][lo1]);
      gA0 += 32; gA1 += 32; gB0 += 32; gB1 += 32;
    }
    short8 af[4], bf[4];
    #pragma unroll
    for (int mi = 0; mi < 4; ++mi)
      af[mi] = *(const short8*)&As[cur][(wm + mi * 16 + l15) * 32 + quad * 8];
    #pragma unroll
    for (int ni = 0; ni < 4; ++ni)
      bf[ni] = *(const short8*)&Bs[cur][(wn + ni * 16 + l15) * 32 + quad * 8];
    #pragma unroll
    for (int mi = 0; mi < 4; ++mi)
      #pragma unroll
      for (int ni = 0; ni < 4; ++ni)
        acc[mi][ni] = __builtin_amdgcn_mfma_f32_16x16x32_bf16(af[mi], bf[ni], acc[mi][ni], 0, 0, 0);
  }

  #pragma unroll
  for (int mi = 0; mi < 4; ++mi)
    #pragma unroll
    for (int ni = 0; ni < 4; ++ni) {
      if (MODE == 0 && blockIdx.z == 2) {
        int mb = m0 + wm + mi * 16 + quad * 4;
        int n  = n0 + wn + ni * 16 + l15;
        int b = mb >> 11, s = mb & 2047, h = n >> 6, d = n & 63;
        u16* out = (u16*)outp + (((size_t)2) << 23);
        h2 p0 = __builtin_amdgcn_cvt_pkrtz(acc[mi][ni][0], acc[mi][ni][1]);
        h2 p1 = __builtin_amdgcn_cvt_pkrtz(acc[mi][ni][2], acc[mi][ni][3]);
        ushort4 o;
        memcpy(&o.x, &p0, 4);
        memcpy(&o.z, &p1, 4);
        *(ushort4*)&out[((((size_t)b * 16 + h) * 64 + d) << 11) + s] = o;
      } else {
        #pragma unroll
        for (int r = 0; r < 4; ++r) {
          int m = m0 + wm + mi * 16 + quad * 4 + r;
          int n = n0 + wn + ni * 16 + l15;
          float v = acc[mi][ni][r];
          if (MODE == 0) {
            int b = m >> 11, s = m & 2047, h = n >> 6, d = n & 63;
            u16* out = (u16*)outp + (((size_t)blockIdx.z) << 23);
            out[((((size_t)b * 16 + h) * 2048 + s) << 6) + d] = f2b(v);
          } else {
            ((float*)outp)[(size_t)m * N + n] = v + bias[n];
          }
        }
      }
    }
}

// ---------- MFMA flash attention, 32x32x16 structure ----------
// Per wave: 32 q rows (q = wave*32 + l31). Per iter (64 keys):
//   S^T = K·Q^T : 2 k-tiles x 4 d-steps of 32x32x16_bf16  (8 MFMA)
//   PV  = V^T·P : 2 d-tiles x 4 k-steps of 32x32x16_f16   (8 MFMA)
// P redistribution (T12): accS C-layout row = (r&3)+8*(r>>2)+4*hi (hi=lane>>5).
// PV B-frag needs k = 16*s + 8*hi' + j  ->  source (hi = j>>2, r = 4*(2*sl+hi')+(j&3)).
// With dwords d[i] = pack_f16(p[2i], p[2i+1]):
//   F0,F2 = permlane32_swap(d[4sl], d[4sl+2]);  F1,F3 = permlane32_swap(d[4sl+1], d[4sl+3])
// lsum: f32 VALU accumulation (covers this lane's 32 of 64 k-rows) + shfl_xor(32) at end.
// Ks AND Vs: unpadded [64][64], 16B-chunk XOR swizzle (chunk ^= row&7) -> conflict-free b128.
__global__ __launch_bounds__(256, 4) void attn_mfma_kernel(
    const u16* __restrict__ qb, const u16* __restrict__ kb, const u16* __restrict__ vtb,
    const float* __restrict__ bias_table, u16* __restrict__ ctx) {
  __shared__ __attribute__((aligned(16))) u16 Ks[2][64 * 64];  // dbuf, XOR-swizzled
  __shared__ __attribute__((aligned(16))) u16 Vs[64 * 64];     // [d][k] fp16, XOR-swizzled
  __shared__ __attribute__((aligned(16))) float bias_s[2304];  // pre-scaled by log2(e)

  const int tid  = threadIdx.x;
  const int wave = tid >> 6, lane = tid & 63;
  const int l31  = lane & 31, hi = lane >> 5;
  const int xsw  = l31 & 7;
  const int bh   = blockIdx.x, h = bh & 15, b = bh >> 4;
  const int q0   = blockIdx.y * 128;

  for (int i = tid; i < 2175; i += 256)
    bias_s[i] = bias_table[(q0 + i) * 16 + h] * 1.44269504f;

  // Q rows (B-operand frags): n = q = l31, k(=d) = ks*16 + hi*8 + j
  short8 aQ[4];
  #pragma unroll
  for (int ks = 0; ks < 4; ++ks)
    aQ[ks] = *(const short8*)&qb[((size_t)bh * 2048 + q0 + wave * 32 + l31) * 64
                                 + ks * 16 + hi * 8];

  f32x16 accO[2] = {};   // O^T tiles: row d = (r&3)+8*(r>>2)+4*hi+32*dt, col q = l31
  float  lsum = 0.f;

  // K staging (global_load_lds, pre-swizzled global source)
  const int krow = lane >> 3;
  const int kchk = (lane & 7) ^ krow;
  const u16* kbase = kb + (((size_t)bh * 2048) << 6);

  // V staging via regs -> swizzled LDS writes
  const int srow = tid >> 2, t0 = tid & 3, ssw = srow & 7;
  const u16* vrow = vtb + (((size_t)bh * 64 + srow) << 11) + t0 * 16;
  const int vo0 = srow * 64 + (((2 * t0    ) ^ ssw) << 3);
  const int vo1 = srow * 64 + (((2 * t0 + 1) ^ ssw) << 3);

  // prologue: prefetch kt=0
  short8 vpre0 = *(const short8*)&vrow[0];
  short8 vpre1 = *(const short8*)&vrow[8];
  #pragma unroll
  for (int g = 0; g < 2; ++g)
    cp16(kbase + (size_t)(wave * 16 + g * 8 + krow) * 64 + kchk * 8,
         &Ks[0][(wave * 16 + g * 8) * 64]);

  for (int kt = 0; kt < 32; ++kt) {
    const int cur = kt & 1;
    __syncthreads();                 // A: drains cp16(kt) + prev-iter Vs reads
    *(short8*)&Vs[vo0] = vpre0;
    *(short8*)&Vs[vo1] = vpre1;
    __syncthreads();                 // B: staged tile visible
    if (kt < 31) {
      const u16* vp = vrow + ((size_t)(kt + 1) << 6);
      vpre0 = *(const short8*)&vp[0];
      vpre1 = *(const short8*)&vp[8];
      #pragma unroll
      for (int g = 0; g < 2; ++g)
        cp16(kbase + (size_t)((kt + 1) * 64 + wave * 16 + g * 8 + krow) * 64 + kchk * 8,
             &Ks[1 - cur][(wave * 16 + g * 8) * 64]);
    }

    #pragma unroll
    for (int t = 0; t < 2; ++t) {
      // ---- S^T tile t: rows k = t*32 + row(r,hi), cols q ----
      f32x16 accS = {};
      #pragma unroll
      for (int ks = 0; ks < 4; ++ks) {
        short8 aK = *(const short8*)&Ks[cur][(t * 32 + l31) * 64
                                            + (((ks * 2 + hi) ^ xsw) << 3)];
        accS = __builtin_amdgcn_mfma_f32_32x32x16_bf16(aK, aQ[ks], accS, 0, 0, 0);
      }

      // ---- softmax: p = exp2(S*log2e/8 + bias*log2e); RNE f16 pack; f32 lsum ----
      u32 d[8];
      const int ib = wave * 32 + l31 - kt * 64 - t * 32 - 4 * hi + 2047;
      #pragma unroll
      for (int rg = 0; rg < 4; ++rg) {
        const int bb = ib - 8 * rg;
        float p0 = __builtin_amdgcn_exp2f(fmaf(accS[4 * rg + 0], 0.18033688f, bias_s[bb    ]));
        float p1 = __builtin_amdgcn_exp2f(fmaf(accS[4 * rg + 1], 0.18033688f, bias_s[bb - 1]));
        float p2 = __builtin_amdgcn_exp2f(fmaf(accS[4 * rg + 2], 0.18033688f, bias_s[bb - 2]));
        float p3 = __builtin_amdgcn_exp2f(fmaf(accS[4 * rg + 3], 0.18033688f, bias_s[bb - 3]));
        lsum += (p0 + p1) + (p2 + p3);
        h2 e0; e0[0] = (__fp16)p0; e0[1] = (__fp16)p1;
        h2 e1; e1[0] = (__fp16)p2; e1[1] = (__fp16)p3;
        memcpy(&d[2 * rg],     &e0, 4);
        memcpy(&d[2 * rg + 1], &e1, 4);
      }

      // ---- redistribute -> PV B-frags, then PV MFMAs ----
      #pragma unroll
      for (int sl = 0; sl < 2; ++sl) {
        u32 F0 = d[4 * sl], F1 = d[4 * sl + 1], F2 = d[4 * sl + 2], F3 = d[4 * sl + 3];
        plswap(F0, F2);
        plswap(F1, F3);
        union { u32 w[4]; h8 v; } uf;
        uf.w[0] = F0; uf.w[1] = F1; uf.w[2] = F2; uf.w[3] = F3;
        const int ch = ((t * 2 + sl) * 2 + hi) ^ xsw;   // k-chunk for this step
        #pragma unroll
        for (int dt = 0; dt < 2; ++dt) {
          short8 av = *(const short8*)&Vs[(dt * 32 + l31) * 64 + (ch << 3)];
          h8 avh; memcpy(&avh, &av, 16);
          accO[dt] = __builtin_amdgcn_mfma_f32_32x32x16_f16(avh, uf.v, accO[dt], 0, 0, 0);
        }
      }
    }
  }

  // ---- epilogue: lane holds half the k-partials -> combine with lane^32 ----
  const float ltot = lsum + __shfl_xor(lsum, 32);
  const float inv  = 1.0f / ltot;
  const int q = q0 + wave * 32 + l31;
  #pragma unroll
  for (int dt = 0; dt < 2; ++dt)
    #pragma unroll
    for (int rg = 0; rg < 4; ++rg) {
      ushort4 o = make_ushort4(f2b(accO[dt][4 * rg + 0] * inv), f2b(accO[dt][4 * rg + 1] * inv),
                               f2b(accO[dt][4 * rg + 2] * inv), f2b(accO[dt][4 * rg + 3] * inv));
      *(ushort4*)&ctx[((size_t)b * 2048 + q) * 1024 + h * 64 + dt * 32 + rg * 8 + hi * 4] = o;
    }
}

// ---------- launch ----------
extern "C" void kernel_launch(void* const* d_in, const int* in_sizes, int n_in,
                              void* d_out, int out_size, void* d_ws, size_t ws_size,
                              hipStream_t stream) {
  const float* x          = (const float*)d_in[0];
  const float* Wq         = (const float*)d_in[1];
  const float* Wk         = (const float*)d_in[2];
  const float* Wv         = (const float*)d_in[3];
  const float* Wo         = (const float*)d_in[4];
  const float* bo         = (const float*)d_in[5];
  const float* bias_table = (const float*)d_in[6];
  float* out = (float*)d_out;

  char* ws = (char*)d_ws;
  u16* xb   = (u16*)(ws);
  u16* wqb  = (u16*)(ws + 16777216);           // Wq,Wk,Wv,Wo bf16 contiguous
  u16* wob  = (u16*)(ws + 16777216 + 3 * 2097152);
  u16* qb   = (u16*)(ws + 25165824);           // q/k/v(t) contiguous, 16 MB each
  u16* kb   = qb + 8388608;
  u16* vtb  = kb + 8388608;                    // V stored [B,H,hd,S] as fp16
  u16* ctxb = (u16*)(ws + 75497472);

  cvt_f2b_kernel<<<8192, 256, 0, stream>>>(x, xb, 8388608);
  cvtw_kernel<<<dim3(1024, 4), 256, 0, stream>>>(Wq, Wk, Wv, Wo, wqb);

  gemm128_bt<0><<<dim3(64, 8, 3), 256, 0, stream>>>(
      xb, wqb, (void*)qb, nullptr, 8192, 1024, 1024);

  attn_mfma_kernel<<<dim3(64, 16), 256, 0, stream>>>(qb, kb, vtb, bias_table, ctxb);

  gemm128_bt<1><<<dim3(64, 8), 256, 0, stream>>>(
      ctxb, wob, (void*)out, bo, 8192, 1024, 1024);
}

// Round 2
// 276.005 us; speedup vs baseline: 1.0630x; 1.0630x over previous
//
#include <hip/hip_runtime.h>
#include <string.h>

typedef unsigned short u16;
typedef unsigned int   u32;
typedef __attribute__((ext_vector_type(8))) short short8;     // 8 bf16/fp16 = 4 VGPRs
typedef __attribute__((ext_vector_type(4))) float f32x4;
typedef __attribute__((ext_vector_type(16))) float f32x16;
typedef __attribute__((ext_vector_type(2))) __fp16 h2;
typedef __attribute__((ext_vector_type(8))) __fp16 h8;
typedef __attribute__((ext_vector_type(2))) unsigned int u32x2;

// ---------- helpers ----------
__device__ __forceinline__ u16 f2b(float f) {                 // fp32 -> bf16 (RNE)
  u32 u = __float_as_uint(f);
  u32 r = (u + 0x7fffu + ((u >> 16) & 1u)) >> 16;
  return (u16)r;
}
// async global->LDS, 16B per lane; LDS dest = wave-uniform base + lane*16
__device__ __forceinline__ void cp16(const u16* g, u16* l) {
  __builtin_amdgcn_global_load_lds(
      (const __attribute__((address_space(1))) void*)g,
      (__attribute__((address_space(3))) void*)l, 16, 0, 0);
}
// v_permlane32_swap: a' = {a.lo32 | b.lo32}, b' = {a.hi32 | b.hi32}
__device__ __forceinline__ void plswap(u32& a, u32& b) {
  u32x2 r = __builtin_amdgcn_permlane32_swap(a, b, false, false);
  a = r[0]; b = r[1];
}

// ---------- fp32 -> bf16 conversion ----------
__global__ __launch_bounds__(256) void cvt_f2b_kernel(const float* __restrict__ in,
                                                      u16* __restrict__ out, int n) {
  int i = (blockIdx.x * 256 + threadIdx.x) * 4;
  if (i + 3 < n) {
    float4 v = *(const float4*)&in[i];
    ushort4 o = make_ushort4(f2b(v.x), f2b(v.y), f2b(v.z), f2b(v.w));
    *(ushort4*)&out[i] = o;
  }
}
// 4 weight matrices in one launch (blockIdx.y selects)
__global__ __launch_bounds__(256) void cvtw_kernel(const float* __restrict__ w0,
                                                   const float* __restrict__ w1,
                                                   const float* __restrict__ w2,
                                                   const float* __restrict__ w3,
                                                   u16* __restrict__ out) {
  const float* src = (blockIdx.y == 0) ? w0 : (blockIdx.y == 1) ? w1
                   : (blockIdx.y == 2) ? w2 : w3;
  int i = (blockIdx.x * 256 + threadIdx.x) * 4;
  float4 v = *(const float4*)&src[i];
  ushort4 o = make_ushort4(f2b(v.x), f2b(v.y), f2b(v.z), f2b(v.w));
  *(ushort4*)&out[(size_t)blockIdx.y * 1048576 + i] = o;
}

// ---------- bf16 MFMA GEMM, BK=32, SINGLE-BARRIER DBUF PIPELINE ----------
// (unchanged this round)
template<int MODE>
__global__ __launch_bounds__(256) void gemm128_bt(
    const u16* __restrict__ A, const u16* __restrict__ Bw,
    void* __restrict__ outp, const float* __restrict__ bias,
    const int M, const int N, const int K) {
  __shared__ __attribute__((aligned(16))) u16 As[2][128 * 32];
  __shared__ __attribute__((aligned(16))) u16 Bs[2][128 * 32];

  const u16* Bw2 = Bw;
  if (MODE == 0) Bw2 += ((size_t)blockIdx.z) << 20;

  const int tid  = threadIdx.x;
  const int wave = tid >> 6, lane = tid & 63;
  const int quad = lane >> 4, l15 = lane & 15;
  const int wm   = (wave >> 1) * 64, wn = (wave & 1) * 64;
  const int m0   = blockIdx.x * 128, n0 = blockIdx.y * 128;

  const int srow = wave * 32 + (lane >> 2);
  const int scol = (lane & 3) * 8;
  const u16* gA0 = A   + (size_t)(m0 + srow) * K + scol;
  const u16* gA1 = gA0 + (size_t)16 * K;
  const u16* gB0 = Bw2 + (size_t)(n0 + srow) * K + scol;
  const u16* gB1 = gB0 + (size_t)16 * K;
  const int lo0 = (wave * 32) * 32, lo1 = (wave * 32 + 16) * 32;

  cp16(gA0, &As[0][lo0]); cp16(gA1, &As[0][lo1]);
  cp16(gB0, &Bs[0][lo0]); cp16(gB1, &Bs[0][lo1]);
  gA0 += 32; gA1 += 32; gB0 += 32; gB1 += 32;

  f32x4 acc[4][4] = {};
  const int nk = K >> 5;
  for (int kt = 0; kt < nk; ++kt) {
    const int cur = kt & 1;
    __syncthreads();
    if (kt + 1 < nk) {
      cp16(gA0, &As[1 - cur][lo0]); cp16(gA1, &As[1 - cur][lo1]);
      cp16(gB0, &Bs[1 - cur][lo0]); cp16(gB1, &Bs[1 - cur][lo1]);
      gA0 += 32; gA1 += 32; gB0 += 32; gB1 += 32;
    }
    short8 af[4], bf[4];
    #pragma unroll
    for (int mi = 0; mi < 4; ++mi)
      af[mi] = *(const short8*)&As[cur][(wm + mi * 16 + l15) * 32 + quad * 8];
    #pragma unroll
    for (int ni = 0; ni < 4; ++ni)
      bf[ni] = *(const short8*)&Bs[cur][(wn + ni * 16 + l15) * 32 + quad * 8];
    #pragma unroll
    for (int mi = 0; mi < 4; ++mi)
      #pragma unroll
      for (int ni = 0; ni < 4; ++ni)
        acc[mi][ni] = __builtin_amdgcn_mfma_f32_16x16x32_bf16(af[mi], bf[ni], acc[mi][ni], 0, 0, 0);
  }

  #pragma unroll
  for (int mi = 0; mi < 4; ++mi)
    #pragma unroll
    for (int ni = 0; ni < 4; ++ni) {
      if (MODE == 0 && blockIdx.z == 2) {
        int mb = m0 + wm + mi * 16 + quad * 4;
        int n  = n0 + wn + ni * 16 + l15;
        int b = mb >> 11, s = mb & 2047, h = n >> 6, d = n & 63;
        u16* out = (u16*)outp + (((size_t)2) << 23);
        h2 p0 = __builtin_amdgcn_cvt_pkrtz(acc[mi][ni][0], acc[mi][ni][1]);
        h2 p1 = __builtin_amdgcn_cvt_pkrtz(acc[mi][ni][2], acc[mi][ni][3]);
        ushort4 o;
        memcpy(&o.x, &p0, 4);
        memcpy(&o.z, &p1, 4);
        *(ushort4*)&out[((((size_t)b * 16 + h) * 64 + d) << 11) + s] = o;
      } else {
        #pragma unroll
        for (int r = 0; r < 4; ++r) {
          int m = m0 + wm + mi * 16 + quad * 4 + r;
          int n = n0 + wn + ni * 16 + l15;
          float v = acc[mi][ni][r];
          if (MODE == 0) {
            int b = m >> 11, s = m & 2047, h = n >> 6, d = n & 63;
            u16* out = (u16*)outp + (((size_t)blockIdx.z) << 23);
            out[((((size_t)b * 16 + h) * 2048 + s) << 6) + d] = f2b(v);
          } else {
            ((float*)outp)[(size_t)m * N + n] = v + bias[n];
          }
        }
      }
    }
}

// ---------- MFMA flash attention, 32x32x16, 64 q-rows/wave, 1 barrier/iter ----------
// Wave owns q = q0 + wave*64 + qs*32 + l31 (qs=0,1). Per iter (64 keys):
//   S^T = K·Q^T : 2 k-subtiles x 4 d-steps x 2 qs of 32x32x16_bf16  (16 MFMA)
//   PV  = V^T·P : 2 d-tiles x 4 k-steps x 2 qs of 32x32x16_f16      (16 MFMA)
// K/V LDS reads (8+8 b128) are SHARED across both qs -> 2x amortization vs r1.
// Ks AND Vs double-buffered; ONE barrier per iter: after barrier, stage tile kt+1
// into buf[1-cur] (cp16 for K, reg->LDS for V), then compute on buf[cur]. The
// barrier's vmcnt(0) drain is one full compute phase after issue.
// P redistribution (T12): accS row = (r&3)+8*(r>>2)+4*hi; dwords d[i]=pack(p2i,p2i+1);
// F0,F2 = plswap(d[4sl],d[4sl+2]); F1,F3 = plswap(d[4sl+1],d[4sl+3]).
// lsum: f32 VALU accumulation + shfl_xor(32) at end.
// XOR-chunk swizzle f(row)=row&7 on both K and V (16B chunks).
__global__ __launch_bounds__(256, 2) void attn_mfma_kernel(
    const u16* __restrict__ qb, const u16* __restrict__ kb, const u16* __restrict__ vtb,
    const float* __restrict__ bias_table, u16* __restrict__ ctx) {
  __shared__ __attribute__((aligned(16))) u16 Ks[2][64 * 64];  // dbuf, XOR-swizzled
  __shared__ __attribute__((aligned(16))) u16 Vs[2][64 * 64];  // dbuf, [d][k] fp16, XOR-swizzled
  __shared__ __attribute__((aligned(16))) float bias_s[2304];  // pre-scaled by log2(e)

  const int tid  = threadIdx.x;
  const int wave = tid >> 6, lane = tid & 63;
  const int l31  = lane & 31, hi = lane >> 5;
  const int xsw  = l31 & 7;
  const int bh   = blockIdx.x, h = bh & 15, b = bh >> 4;
  const int q0   = blockIdx.y * 256;

  for (int i = tid; i < 2303; i += 256)
    bias_s[i] = bias_table[(q0 + i) * 16 + h] * 1.44269504f;

  // Q B-frags: n = q, k(=d) = ks*16 + hi*8 + j
  short8 aQ[2][4];
  #pragma unroll
  for (int qs = 0; qs < 2; ++qs)
    #pragma unroll
    for (int ks = 0; ks < 4; ++ks)
      aQ[qs][ks] = *(const short8*)&qb[((size_t)bh * 2048 + q0 + wave * 64 + qs * 32 + l31) * 64
                                       + ks * 16 + hi * 8];

  f32x16 accO[2][2] = {};   // [qs][dt]; row d = (r&3)+8*(r>>2)+4*hi+32*dt, col q = l31
  float  lsum[2] = {0.f, 0.f};

  // K staging (global_load_lds, pre-swizzled global source)
  const int krow = lane >> 3;
  const int kchk = (lane & 7) ^ krow;
  const u16* kbase = kb + (((size_t)bh * 2048) << 6);

  // V staging via regs -> swizzled LDS writes
  const int srow = tid >> 2, t0 = tid & 3, ssw = srow & 7;
  const u16* vrow = vtb + (((size_t)bh * 64 + srow) << 11) + t0 * 16;
  const int vo0 = srow * 64 + (((2 * t0    ) ^ ssw) << 3);
  const int vo1 = srow * 64 + (((2 * t0 + 1) ^ ssw) << 3);

  // prologue: stage tile 0, prefetch tile 1 regs
  short8 vpre0 = *(const short8*)&vrow[0];
  short8 vpre1 = *(const short8*)&vrow[8];
  *(short8*)&Vs[0][vo0] = vpre0;           // compiler inserts vmcnt wait
  *(short8*)&Vs[0][vo1] = vpre1;
  #pragma unroll
  for (int g = 0; g < 2; ++g)
    cp16(kbase + (size_t)(wave * 16 + g * 8 + krow) * 64 + kchk * 8,
         &Ks[0][(wave * 16 + g * 8) * 64]);
  vpre0 = *(const short8*)&vrow[64];
  vpre1 = *(const short8*)&vrow[72];

  for (int kt = 0; kt < 32; ++kt) {
    const int cur = kt & 1;
    __syncthreads();   // drains cp16(kt) + vpre loads; makes Vs[cur] writes visible
    if (kt < 31) {
      #pragma unroll
      for (int g = 0; g < 2; ++g)
        cp16(kbase + (size_t)((kt + 1) * 64 + wave * 16 + g * 8 + krow) * 64 + kchk * 8,
             &Ks[1 - cur][(wave * 16 + g * 8) * 64]);
      *(short8*)&Vs[1 - cur][vo0] = vpre0;   // V(kt+1), already landed (drained at barrier)
      *(short8*)&Vs[1 - cur][vo1] = vpre1;
      if (kt < 30) {
        const u16* vp = vrow + ((size_t)(kt + 2) << 6);
        vpre0 = *(const short8*)&vp[0];
        vpre1 = *(const short8*)&vp[8];
      }
    }

    #pragma unroll
    for (int t = 0; t < 2; ++t) {
      // ---- S^T tile t: rows k = t*32 + row(r,hi), cols q; aK shared across qs ----
      short8 aK[4];
      #pragma unroll
      for (int ks = 0; ks < 4; ++ks)
        aK[ks] = *(const short8*)&Ks[cur][(t * 32 + l31) * 64
                                          + (((ks * 2 + hi) ^ xsw) << 3)];
      f32x16 accS[2] = {};
      #pragma unroll
      for (int ks = 0; ks < 4; ++ks)
        #pragma unroll
        for (int qs = 0; qs < 2; ++qs)
          accS[qs] = __builtin_amdgcn_mfma_f32_32x32x16_bf16(aK[ks], aQ[qs][ks], accS[qs], 0, 0, 0);

      // ---- softmax: p = exp2(S*log2e/8 + bias*log2e); RNE f16 pack; f32 lsum ----
      u32 d[2][8];
      #pragma unroll
      for (int qs = 0; qs < 2; ++qs) {
        const int ib = wave * 64 + qs * 32 + l31 - kt * 64 - t * 32 - 4 * hi + 2047;
        #pragma unroll
        for (int rg = 0; rg < 4; ++rg) {
          const int bb = ib - 8 * rg;
          float p0 = __builtin_amdgcn_exp2f(fmaf(accS[qs][4 * rg + 0], 0.18033688f, bias_s[bb    ]));
          float p1 = __builtin_amdgcn_exp2f(fmaf(accS[qs][4 * rg + 1], 0.18033688f, bias_s[bb - 1]));
          float p2 = __builtin_amdgcn_exp2f(fmaf(accS[qs][4 * rg + 2], 0.18033688f, bias_s[bb - 2]));
          float p3 = __builtin_amdgcn_exp2f(fmaf(accS[qs][4 * rg + 3], 0.18033688f, bias_s[bb - 3]));
          lsum[qs] += (p0 + p1) + (p2 + p3);
          h2 e0; e0[0] = (__fp16)p0; e0[1] = (__fp16)p1;
          h2 e1; e1[0] = (__fp16)p2; e1[1] = (__fp16)p3;
          memcpy(&d[qs][2 * rg],     &e0, 4);
          memcpy(&d[qs][2 * rg + 1], &e1, 4);
        }
      }

      // ---- PV: V reads shared across qs ----
      #pragma unroll
      for (int sl = 0; sl < 2; ++sl) {
        const int ch = ((t * 2 + sl) * 2 + hi) ^ xsw;   // k-chunk for this step
        short8 av0 = *(const short8*)&Vs[cur][(     l31) * 64 + (ch << 3)];
        short8 av1 = *(const short8*)&Vs[cur][(32 + l31) * 64 + (ch << 3)];
        h8 avh0, avh1;
        memcpy(&avh0, &av0, 16);
        memcpy(&avh1, &av1, 16);
        #pragma unroll
        for (int qs = 0; qs < 2; ++qs) {
          u32 F0 = d[qs][4 * sl], F1 = d[qs][4 * sl + 1];
          u32 F2 = d[qs][4 * sl + 2], F3 = d[qs][4 * sl + 3];
          plswap(F0, F2);
          plswap(F1, F3);
          union { u32 w[4]; h8 v; } uf;
          uf.w[0] = F0; uf.w[1] = F1; uf.w[2] = F2; uf.w[3] = F3;
          accO[qs][0] = __builtin_amdgcn_mfma_f32_32x32x16_f16(avh0, uf.v, accO[qs][0], 0, 0, 0);
          accO[qs][1] = __builtin_amdgcn_mfma_f32_32x32x16_f16(avh1, uf.v, accO[qs][1], 0, 0, 0);
        }
      }
    }
  }

  // ---- epilogue: lane holds half the k-partials -> combine with lane^32 ----
  #pragma unroll
  for (int qs = 0; qs < 2; ++qs) {
    const float ltot = lsum[qs] + __shfl_xor(lsum[qs], 32);
    const float inv  = 1.0f / ltot;
    const int q = q0 + wave * 64 + qs * 32 + l31;
    #pragma unroll
    for (int dt = 0; dt < 2; ++dt)
      #pragma unroll
      for (int rg = 0; rg < 4; ++rg) {
        ushort4 o = make_ushort4(f2b(accO[qs][dt][4 * rg + 0] * inv), f2b(accO[qs][dt][4 * rg + 1] * inv),
                                 f2b(accO[qs][dt][4 * rg + 2] * inv), f2b(accO[qs][dt][4 * rg + 3] * inv));
        *(ushort4*)&ctx[((size_t)b * 2048 + q) * 1024 + h * 64 + dt * 32 + rg * 8 + hi * 4] = o;
      }
  }
}

// ---------- launch ----------
extern "C" void kernel_launch(void* const* d_in, const int* in_sizes, int n_in,
                              void* d_out, int out_size, void* d_ws, size_t ws_size,
                              hipStream_t stream) {
  const float* x          = (const float*)d_in[0];
  const float* Wq         = (const float*)d_in[1];
  const float* Wk         = (const float*)d_in[2];
  const float* Wv         = (const float*)d_in[3];
  const float* Wo         = (const float*)d_in[4];
  const float* bo         = (const float*)d_in[5];
  const float* bias_table = (const float*)d_in[6];
  float* out = (float*)d_out;

  char* ws = (char*)d_ws;
  u16* xb   = (u16*)(ws);
  u16* wqb  = (u16*)(ws + 16777216);           // Wq,Wk,Wv,Wo bf16 contiguous
  u16* wob  = (u16*)(ws + 16777216 + 3 * 2097152);
  u16* qb   = (u16*)(ws + 25165824);           // q/k/v(t) contiguous, 16 MB each
  u16* kb   = qb + 8388608;
  u16* vtb  = kb + 8388608;                    // V stored [B,H,hd,S] as fp16
  u16* ctxb = (u16*)(ws + 75497472);

  cvt_f2b_kernel<<<8192, 256, 0, stream>>>(x, xb, 8388608);
  cvtw_kernel<<<dim3(1024, 4), 256, 0, stream>>>(Wq, Wk, Wv, Wo, wqb);

  gemm128_bt<0><<<dim3(64, 8, 3), 256, 0, stream>>>(
      xb, wqb, (void*)qb, nullptr, 8192, 1024, 1024);

  attn_mfma_kernel<<<dim3(64, 8), 256, 0, stream>>>(qb, kb, vtb, bias_table, ctxb);

  gemm128_bt<1><<<dim3(64, 8), 256, 0, stream>>>(
      ctxb, wob, (void*)out, bo, 8192, 1024, 1024);
}